// Round 7
// baseline (807.499 us; speedup 1.0000x reference)
//
#include <hip/hip_runtime.h>

namespace {

constexpr int NNODES = 50000;
constexpr int NEDGES = 800000;
constexpr int NBUCK  = (NNODES + 127) / 128;  // 391 buckets of 128 dst nodes
constexpr int BCAP   = 3072;                  // bucket capacity: mean 2048, sigma~45 -> 22 sigma slack
constexpr int SB     = 64;                    // scatter/hist blocks
constexpr int CHUNK  = NEDGES / SB;           // 12500 edges per block (exact)

// ---------------------------------------------------------------------------
// Detect whether edge_index arrived as int64 (odd 32-bit words all zero,
// since values < 50000) or int32 (odd words are values, ~never zero).
__global__ __launch_bounds__(256) void detect_idx64(const unsigned int* __restrict__ raw,
                                                    int* __restrict__ flag) {
  __shared__ int s_any;
  if (threadIdx.x == 0) s_any = 0;
  __syncthreads();
  int any = 0;
  for (int i = 1 + 2 * (int)threadIdx.x; i < 8192; i += 512) {
    any |= (raw[i] != 0u) ? 1 : 0;
  }
  if (any) atomicOr(&s_any, 1);
  __syncthreads();
  if (threadIdx.x == 0) *flag = (s_any == 0) ? 1 : 0;
}

// ---------------------------------------------------------------------------
// ROUND-6 LESSON: 800K global atomicAdd over 391 cursors = ~2048 serialized
// RMWs/address x ~140ns = 287us. Aggregate per-block in LDS; make global
// offsets deterministic via a per-bucket scan. Zero global atomics below.

// Phase 1: per-block LDS histogram over buckets -> blkhist[bucket*SB + block].
__global__ __launch_bounds__(512) void hist_pass(const void* __restrict__ raw,
                                                 const int* __restrict__ flag,
                                                 int* __restrict__ blkhist) {
  __shared__ int hist[NBUCK];
  for (int i = threadIdx.x; i < NBUCK; i += 512) hist[i] = 0;
  __syncthreads();
  const int is64 = *flag;
  const int b = blockIdx.x;
  const int beg = b * CHUNK, end = beg + CHUNK;
  for (int e = beg + (int)threadIdx.x; e < end; e += 512) {
    const int d = is64 ? (int)((const long long*)raw)[NEDGES + e]
                       : ((const int*)raw)[NEDGES + e];
    atomicAdd(&hist[d >> 7], 1);
  }
  __syncthreads();
  for (int i = threadIdx.x; i < NBUCK; i += 512) blkhist[i * SB + b] = hist[i];
}

// Phase 2: per-bucket exclusive scan over the SB block-counts -> exact write
// offsets into the bucket's fixed-capacity region; also bucket totals.
__global__ __launch_bounds__(64) void col_scan(const int* __restrict__ blkhist,
                                               int* __restrict__ offs,
                                               int* __restrict__ bcount) {
  const int bk = blockIdx.x;
  const int t = threadIdx.x;
  const int c = blkhist[bk * SB + t];
  int s = c;
#pragma unroll
  for (int off = 1; off < 64; off <<= 1) {
    const int u = __shfl_up(s, off, 64);
    if (t >= off) s += u;
  }
  offs[bk * SB + t] = bk * BCAP + (s - c);
  if (t == 63) bcount[bk] = s;
}

// Phase 3: place packed edges (dst<<16 | src, both < 2^16) into bucket
// regions. Per-(block,bucket) runs are contiguous (~32 edges = 128B) ->
// good write-line utilization; LDS cursors only.
__global__ __launch_bounds__(512) void scatter_pass(const void* __restrict__ raw,
                                                    const int* __restrict__ flag,
                                                    const int* __restrict__ offs,
                                                    unsigned int* __restrict__ ebuf) {
  __shared__ int loff[NBUCK];
  __shared__ int lcur[NBUCK];
  const int b = blockIdx.x;
  for (int i = threadIdx.x; i < NBUCK; i += 512) {
    loff[i] = offs[i * SB + b];
    lcur[i] = 0;
  }
  __syncthreads();
  const int is64 = *flag;
  const int beg = b * CHUNK, end = beg + CHUNK;
  for (int e = beg + (int)threadIdx.x; e < end; e += 512) {
    int s, d;
    if (is64) {
      const long long* p = (const long long*)raw;
      s = (int)p[e];
      d = (int)p[NEDGES + e];
    } else {
      const int* p = (const int*)raw;
      s = p[e];
      d = p[NEDGES + e];
    }
    const int bk = d >> 7;
    const unsigned int val = ((unsigned int)d << 16) | (unsigned int)s;
    const int lr = atomicAdd(&lcur[bk], 1);
    ebuf[loff[bk] + lr] = val;
  }
}

// Fused bucket segment-mean: one block per bucket of 128 dst nodes.
// LDS accumulator acc[128][64] + LDS degree counts; lanes = channels.
//   outb[v,c] = (1/max(deg,1)) * sum_{edges into v} xin[src, c]  (+ radd if FINAL)
// Replaces CSR emit + per-node gather entirely.
template <bool FINAL>
__global__ __launch_bounds__(512) void bucket_mean(const float* __restrict__ xin,
                                                   const unsigned int* __restrict__ ebuf,
                                                   const int* __restrict__ bcount,
                                                   const float* __restrict__ radd,
                                                   float* __restrict__ outb) {
  __shared__ float acc[128 * 64];   // 32 KB
  __shared__ int dcnt[128];
  for (int i = threadIdx.x; i < 128 * 64; i += 512) acc[i] = 0.0f;
  if (threadIdx.x < 128) dcnt[threadIdx.x] = 0;
  __syncthreads();

  const int bk = blockIdx.x;
  const int base = bk * 128;
  const int nloc = min(128, NNODES - base);
  const int cnt = bcount[bk];
  const unsigned int* eb = ebuf + (size_t)bk * BCAP;
  const int w = threadIdx.x >> 6;
  const int lane = threadIdx.x & 63;

  constexpr int UNR = 8;  // 8 edges in flight per wave iteration (MLP)
  for (int e0 = w * UNR; e0 < cnt; e0 += 8 * UNR) {
    const int m = min(UNR, cnt - e0);
    unsigned int vals[UNR];
#pragma unroll
    for (int j = 0; j < UNR; ++j) vals[j] = (j < m) ? eb[e0 + j] : 0u;
    float xv[UNR];
    int loc[UNR];
#pragma unroll
    for (int j = 0; j < UNR; ++j) {
      loc[j] = (int)((vals[j] >> 16) & 127u);
      const int src = (int)(vals[j] & 0xFFFFu);
      xv[j] = (j < m) ? xin[(size_t)src * 64 + lane] : 0.0f;
    }
#pragma unroll
    for (int j = 0; j < UNR; ++j) {
      if (j < m) {
        atomicAdd(&acc[loc[j] * 64 + lane], xv[j]);   // ds_add_f32, lanes on distinct banks
        if (lane == j) atomicAdd(&dcnt[loc[j]], 1);   // spread across 8 lanes
      }
    }
  }
  __syncthreads();

  for (int i = threadIdx.x; i < nloc * 64; i += 512) {
    const int l = i >> 6;
    float v = acc[i] / (float)max(dcnt[l], 1);
    const size_t gi = (size_t)(base + l) * 64 + (i & 63);
    if (FINAL) v += radd[gi];
    outb[gi] = v;
  }
}

// ---------------------------------------------------------------------------
// Register-tiled fp32 GEMM: C[50000 x 128] = A[50000 x 128] @ W[128 x 128].
// MODE 0 (layer 1): A = [mean1 | x], W = [Wl1 ; Wr1], out = relu(C+b) -> O0[N,128]
// MODE 1 (layer 2): A = h, W = [Wl2 | Wr2],
//                   O0[N,64] = C[:,0:64] (p); O1[N,64] = C[:,64:128] + b (r)
// ROUND-4 LESSON: do NOT unroll the outer ck loop (VGPR blowout -> scratch
// spill, 2.2 GB/dispatch, 15x slowdown). unroll 1 + 3 blocks/CU bound.
template <int MODE>
__global__ __launch_bounds__(256, 3) void gemm128(const float* __restrict__ A0,
                                                  const float* __restrict__ A1,
                                                  const float* __restrict__ W0,
                                                  const float* __restrict__ W1,
                                                  const float* __restrict__ bias,
                                                  float* __restrict__ O0,
                                                  float* __restrict__ O1) {
  constexpr int SAS = 36;  // sA row stride (pad 32->36: rows land on distinct banks)
  __shared__ float sA[64][SAS];
  __shared__ float sW[32][128];
  const int row0 = blockIdx.x * 64;
  const int tid = threadIdx.x;
  const int rowgrp = tid >> 4;   // 0..15
  const int colgrp = tid & 15;   // 0..15
  const int r0 = rowgrp * 4;
  const int j0 = colgrp * 4;

  float accA[4][4];  // cols j0..j0+3
  float accB[4][4];  // cols 64+j0..64+j0+3
#pragma unroll
  for (int r = 0; r < 4; ++r)
#pragma unroll
    for (int c = 0; c < 4; ++c) { accA[r][c] = 0.0f; accB[r][c] = 0.0f; }

#pragma unroll 1   // keep ONE copy of the body (see round-4 lesson above)
  for (int ck = 0; ck < 4; ++ck) {
    // --- stage sA: 64 rows x 32 k ---
#pragma unroll
    for (int v = 0; v < 2; ++v) {
      const int vid = v * 256 + tid;       // 0..511
      const int rr = vid >> 3;             // 0..63
      const int kq = (vid & 7) * 4;        // 0,4,...,28
      const int grow = row0 + rr;
      float4 val = make_float4(0.f, 0.f, 0.f, 0.f);
      if (grow < NNODES) {
        if (MODE == 0) {
          const float* src = (ck < 2) ? A0 : A1;
          const int kk = (ck & 1) * 32 + kq;
          val = *(const float4*)&src[(size_t)grow * 64 + kk];
        } else {
          val = *(const float4*)&A0[(size_t)grow * 128 + ck * 32 + kq];
        }
      }
      *(float4*)&sA[rr][kq] = val;
    }
    // --- stage sW: 32 k x 128 j ---
#pragma unroll
    for (int v = 0; v < 4; ++v) {
      const int vid = v * 256 + tid;       // 0..1023
      const int kk = vid >> 5;             // 0..31
      const int jq = (vid & 31) * 4;       // 0,4,...,124
      float4 w;
      if (MODE == 0) {
        const float* src = (ck < 2) ? W0 : W1;
        const int krel = (ck & 1) * 32 + kk;
        w = *(const float4*)&src[(size_t)krel * 128 + jq];
      } else {
        const int kg = ck * 32 + kk;
        const float* src = (jq < 64) ? W0 : W1;
        const int jrel = (jq < 64) ? jq : jq - 64;
        w = *(const float4*)&src[(size_t)kg * 64 + jrel];
      }
      *(float4*)&sW[kk][jq] = w;
    }
    __syncthreads();
    // --- compute: 32 k's, 128 FMA per 4-k group per thread ---
#pragma unroll
    for (int k4 = 0; k4 < 8; ++k4) {
      float4 a[4];
#pragma unroll
      for (int r = 0; r < 4; ++r) a[r] = *(const float4*)&sA[r0 + r][k4 * 4];
#pragma unroll
      for (int ki = 0; ki < 4; ++ki) {
        const float4 wlo = *(const float4*)&sW[k4 * 4 + ki][j0];
        const float4 whi = *(const float4*)&sW[k4 * 4 + ki][64 + j0];
#pragma unroll
        for (int r = 0; r < 4; ++r) {
          const float av = (ki == 0) ? a[r].x : (ki == 1) ? a[r].y
                         : (ki == 2) ? a[r].z : a[r].w;
          accA[r][0] = fmaf(av, wlo.x, accA[r][0]);
          accA[r][1] = fmaf(av, wlo.y, accA[r][1]);
          accA[r][2] = fmaf(av, wlo.z, accA[r][2]);
          accA[r][3] = fmaf(av, wlo.w, accA[r][3]);
          accB[r][0] = fmaf(av, whi.x, accB[r][0]);
          accB[r][1] = fmaf(av, whi.y, accB[r][1]);
          accB[r][2] = fmaf(av, whi.z, accB[r][2]);
          accB[r][3] = fmaf(av, whi.w, accB[r][3]);
        }
      }
    }
    __syncthreads();
  }

  // --- epilogue ---
  float4 blo = make_float4(0.f, 0.f, 0.f, 0.f);
  float4 bhi;
  if (MODE == 0) {
    blo = *(const float4*)&bias[j0];
    bhi = *(const float4*)&bias[64 + j0];
  } else {
    bhi = *(const float4*)&bias[j0];  // bias applies to r (upper half)
  }
#pragma unroll
  for (int r = 0; r < 4; ++r) {
    const int grow = row0 + r0 + r;
    if (grow >= NNODES) continue;
    float4 lo = make_float4(accA[r][0] + blo.x, accA[r][1] + blo.y,
                            accA[r][2] + blo.z, accA[r][3] + blo.w);
    float4 hi = make_float4(accB[r][0] + bhi.x, accB[r][1] + bhi.y,
                            accB[r][2] + bhi.z, accB[r][3] + bhi.w);
    if (MODE == 0) {
      lo.x = fmaxf(lo.x, 0.f); lo.y = fmaxf(lo.y, 0.f);
      lo.z = fmaxf(lo.z, 0.f); lo.w = fmaxf(lo.w, 0.f);
      hi.x = fmaxf(hi.x, 0.f); hi.y = fmaxf(hi.y, 0.f);
      hi.z = fmaxf(hi.z, 0.f); hi.w = fmaxf(hi.w, 0.f);
      *(float4*)&O0[(size_t)grow * 128 + j0] = lo;
      *(float4*)&O0[(size_t)grow * 128 + 64 + j0] = hi;
    } else {
      *(float4*)&O0[(size_t)grow * 64 + j0] = lo;   // p (no bias; blo==0)
      *(float4*)&O1[(size_t)grow * 64 + j0] = hi;   // r (+bl2)
    }
  }
}

}  // namespace

extern "C" void kernel_launch(void* const* d_in, const int* in_sizes, int n_in,
                              void* d_out, int out_size, void* d_ws, size_t ws_size,
                              hipStream_t stream) {
  const float* x   = (const float*)d_in[0];
  const void*  ei  = d_in[1];  // edge_index, int32 or int64 (detected at runtime)
  const float* Wl1 = (const float*)d_in[2];
  const float* bl1 = (const float*)d_in[3];
  const float* Wr1 = (const float*)d_in[4];
  const float* Wl2 = (const float*)d_in[5];
  const float* bl2 = (const float*)d_in[6];
  const float* Wr2 = (const float*)d_in[7];
  float* out = (float*)d_out;

  // Workspace layout (bytes):
  //   flag    [1]          int32 @ 0          (256)
  //   blkhist [NBUCK*SB]   int32 @ 256        (100,096 pad->100,352)
  //   offs    [NBUCK*SB]   int32 @ 100,608    (100,096 pad->100,352)
  //   bcount  [NBUCK]      int32 @ 200,960    (1,564 pad->2,048)
  //   ebuf    [NBUCK*BCAP] u32   @ 203,008    (4,804,608)
  //   mean1   [N,64]       f32   @ 5,007,616  (12,800,000)  -- reused as r
  //   h       [N,128]      f32   @ 17,807,616 (25,600,000)
  //   p       [N,64]       f32   @ 43,407,616 (12,800,000)
  // total: 56,207,616 bytes (round 1 used 70.6 MB successfully)
  char* ws = (char*)d_ws;
  int*          flag    = (int*)(ws + 0);
  int*          blkhist = (int*)(ws + 256);
  int*          offs    = (int*)(ws + 100608);
  int*          bcount  = (int*)(ws + 200960);
  unsigned int* ebuf    = (unsigned int*)(ws + 203008);
  float*        mean1   = (float*)(ws + 5007616);
  float*        h       = (float*)(ws + 17807616);
  float*        p       = (float*)(ws + 43407616);
  float*        r       = mean1;  // safe: mean1's last read (gemm128<0>) precedes gemm128<1>'s write

  // Bucketed edge build: histogram -> deterministic offsets -> scatter.
  // No global atomics, no memsets.
  detect_idx64<<<1, 256, 0, stream>>>((const unsigned int*)ei, flag);
  hist_pass<<<SB, 512, 0, stream>>>(ei, flag, blkhist);
  col_scan<<<NBUCK, 64, 0, stream>>>(blkhist, offs, bcount);
  scatter_pass<<<SB, 512, 0, stream>>>(ei, flag, offs, ebuf);

  constexpr int GEMM_BLOCKS = (NNODES + 63) / 64;  // 782

  // Layer 1: fused bucket mean-aggregate of x, then fused linear+relu
  bucket_mean<false><<<NBUCK, 512, 0, stream>>>(x, ebuf, bcount, nullptr, mean1);
  gemm128<0><<<GEMM_BLOCKS, 256, 0, stream>>>(mean1, x, Wl1, Wr1, bl1, h, nullptr);

  // Layer 2: project first (mean commutes with linear), then bucket mean + r
  gemm128<1><<<GEMM_BLOCKS, 256, 0, stream>>>(h, nullptr, Wl2, Wr2, bl2, p, r);
  bucket_mean<true><<<NBUCK, 512, 0, stream>>>(p, ebuf, bcount, r, out);
}

// Round 8
// 178.394 us; speedup vs baseline: 4.5265x; 4.5265x over previous
//
#include <hip/hip_runtime.h>

namespace {

constexpr int NNODES = 50000;
constexpr int NEDGES = 800000;
constexpr int DIN  = 64;
constexpr int DOUT = 64;
constexpr int NBUCK  = (NNODES + 127) / 128;  // 391 buckets of 128 dst nodes
constexpr int BCAP   = 3072;                  // bucket capacity: mean 2048, ~22 sigma slack
constexpr int SB     = 64;                    // scatter/hist blocks
constexpr int CHUNK  = NEDGES / SB;           // 12500 edges per block (exact)

// ROUND-6 LESSON: per-address global atomic ~140ns serialized -> never >1K
// ops/address (bucket_scatter: 2048/address = 287us).
// ROUND-7 LESSON: aggregation must be node-parallel (50K waves, seg_mean),
// never bucket-parallel (391 blocks = 1.5 blocks/CU, latency-starved, 363us).

// ---------------------------------------------------------------------------
// Detect whether edge_index arrived as int64 (odd 32-bit words all zero,
// since values < 50000) or int32 (odd words are values, ~never zero).
__global__ __launch_bounds__(256) void detect_idx64(const unsigned int* __restrict__ raw,
                                                    int* __restrict__ flag) {
  __shared__ int s_any;
  if (threadIdx.x == 0) s_any = 0;
  __syncthreads();
  int any = 0;
  for (int i = 1 + 2 * (int)threadIdx.x; i < 8192; i += 512) {
    any |= (raw[i] != 0u) ? 1 : 0;
  }
  if (any) atomicOr(&s_any, 1);
  __syncthreads();
  if (threadIdx.x == 0) *flag = (s_any == 0) ? 1 : 0;
}

// Phase 1: per-block LDS histogram over buckets -> blkhist[bucket*SB + block].
__global__ __launch_bounds__(512) void hist_pass(const void* __restrict__ raw,
                                                 const int* __restrict__ flag,
                                                 int* __restrict__ blkhist) {
  __shared__ int hist[NBUCK];
  for (int i = threadIdx.x; i < NBUCK; i += 512) hist[i] = 0;
  __syncthreads();
  const int is64 = *flag;
  const int b = blockIdx.x;
  const int beg = b * CHUNK, end = beg + CHUNK;
  for (int e = beg + (int)threadIdx.x; e < end; e += 512) {
    const int d = is64 ? (int)((const long long*)raw)[NEDGES + e]
                       : ((const int*)raw)[NEDGES + e];
    atomicAdd(&hist[d >> 7], 1);
  }
  __syncthreads();
  for (int i = threadIdx.x; i < NBUCK; i += 512) blkhist[i * SB + b] = hist[i];
}

// Phase 2: per-bucket exclusive scan over the SB block-counts -> exact write
// offsets into the bucket's fixed-capacity region; also bucket totals.
__global__ __launch_bounds__(64) void col_scan(const int* __restrict__ blkhist,
                                               int* __restrict__ offs,
                                               int* __restrict__ bcount) {
  const int bk = blockIdx.x;
  const int t = threadIdx.x;
  const int c = blkhist[bk * SB + t];
  int s = c;
#pragma unroll
  for (int off = 1; off < 64; off <<= 1) {
    const int u = __shfl_up(s, off, 64);
    if (t >= off) s += u;
  }
  offs[bk * SB + t] = bk * BCAP + (s - c);
  if (t == 63) bcount[bk] = s;
}

// Exclusive scan of bcount[NBUCK] -> bprefix (bucket base in final col-space).
__global__ __launch_bounds__(512) void bucket_prefix(const int* __restrict__ bcount,
                                                     int* __restrict__ bprefix) {
  __shared__ int sh[512];
  const int t = threadIdx.x;
  const int v = (t < NBUCK) ? bcount[t] : 0;
  sh[t] = v;
  __syncthreads();
#pragma unroll
  for (int off = 1; off < 512; off <<= 1) {
    const int val = sh[t];
    const int add = (t >= off) ? sh[t - off] : 0;
    __syncthreads();
    sh[t] = val + add;
    __syncthreads();
  }
  if (t < NBUCK) bprefix[t] = sh[t] - v;
}

// Phase 3: place packed edges (dst<<16 | src, both < 2^16) into bucket
// regions. Per-(block,bucket) runs are contiguous (~32 edges = 128B) ->
// good write-line utilization; LDS cursors only, zero global atomics.
__global__ __launch_bounds__(512) void scatter_pass(const void* __restrict__ raw,
                                                    const int* __restrict__ flag,
                                                    const int* __restrict__ offs,
                                                    unsigned int* __restrict__ ebuf) {
  __shared__ int loff[NBUCK];
  __shared__ int lcur[NBUCK];
  const int b = blockIdx.x;
  for (int i = threadIdx.x; i < NBUCK; i += 512) {
    loff[i] = offs[i * SB + b];
    lcur[i] = 0;
  }
  __syncthreads();
  const int is64 = *flag;
  const int beg = b * CHUNK, end = beg + CHUNK;
  for (int e = beg + (int)threadIdx.x; e < end; e += 512) {
    int s, d;
    if (is64) {
      const long long* p = (const long long*)raw;
      s = (int)p[e];
      d = (int)p[NEDGES + e];
    } else {
      const int* p = (const int*)raw;
      s = p[e];
      d = p[NEDGES + e];
    }
    const int bk = d >> 7;
    const unsigned int val = ((unsigned int)d << 16) | (unsigned int)s;
    const int lr = atomicAdd(&lcur[bk], 1);
    ebuf[loff[bk] + lr] = val;
  }
}

// Phase 4: one block per bucket. Sort the bucket's edges into final CSR
// order via LDS count+scan+place; ALSO emits row_ptr (replaces deg_hist +
// 3 scan kernels + memset). Edges cached in registers (<=12/thread, static
// indexing) so ebuf is read exactly once. col writes land in one contiguous
// ~8KB region -> full write-line utilization.
__global__ __launch_bounds__(256) void csr_emit2(const unsigned int* __restrict__ ebuf,
                                                 const int* __restrict__ bcount,
                                                 const int* __restrict__ bprefix,
                                                 int* __restrict__ row_ptr,
                                                 int* __restrict__ col) {
  const int bk = blockIdx.x;
  const int base = bk * 128;
  const int nloc = min(128, NNODES - base);
  const int cnt = bcount[bk];          // <= BCAP = 3072 = 12*256
  const int bbase = bprefix[bk];
  const unsigned int* eb = ebuf + (size_t)bk * BCAP;

  __shared__ int dcnt[128];
  __shared__ int loff[128];
  __shared__ int lcur[128];
  if (threadIdx.x < 128) dcnt[threadIdx.x] = 0;
  __syncthreads();

  // pass A: cache edges + per-node counts
  unsigned int vals[12];
  int m = 0;
#pragma unroll
  for (int k = 0; k < 12; ++k) {
    const int e = (int)threadIdx.x + k * 256;
    if (e < cnt) {
      vals[k] = eb[e];
      atomicAdd(&dcnt[(vals[k] >> 16) & 127u], 1);
      m = k + 1;
    }
  }
  __syncthreads();

  // exclusive scan of dcnt[0..127] (Hillis-Steele in LDS)
  if (threadIdx.x < 128) loff[threadIdx.x] = dcnt[threadIdx.x];
  __syncthreads();
#pragma unroll
  for (int off = 1; off < 128; off <<= 1) {
    int add = 0;
    if (threadIdx.x < 128 && (int)threadIdx.x >= off) add = loff[threadIdx.x - off];
    __syncthreads();
    if (threadIdx.x < 128) loff[threadIdx.x] += add;
    __syncthreads();
  }
  if (threadIdx.x < 128) {
    const int excl = loff[threadIdx.x] - dcnt[threadIdx.x];
    loff[threadIdx.x] = excl;
    lcur[threadIdx.x] = 0;
    if ((int)threadIdx.x < nloc) row_ptr[base + threadIdx.x] = bbase + excl;
  }
  if (bk == NBUCK - 1 && threadIdx.x == 0) row_ptr[NNODES] = NEDGES;
  __syncthreads();

  // pass B: place
#pragma unroll
  for (int k = 0; k < 12; ++k) {
    if (k < m) {
      const int loc = (int)((vals[k] >> 16) & 127u);
      const int slot = bbase + loff[loc] + atomicAdd(&lcur[loc], 1);
      col[slot] = (int)(vals[k] & 0xFFFFu);
    }
  }
}

// Segment mean via gather: one wave (64 lanes == D channels) per node.
// (Byte-identical to the round-5 version: 50K waves hide gather latency.)
template <int D, bool FINAL>
__global__ __launch_bounds__(256) void seg_mean(const float* __restrict__ xin,
                                                const int* __restrict__ row_ptr,
                                                const int* __restrict__ col,
                                                const float* __restrict__ radd,
                                                float* __restrict__ outbuf) {
  static_assert(D == 64, "one wave == one node's 64 channels");
  const int lane = threadIdx.x & 63;
  const int wid = (blockIdx.x * blockDim.x + threadIdx.x) >> 6;
  const int nw = (gridDim.x * blockDim.x) >> 6;
  for (int v = wid; v < NNODES; v += nw) {
    const int b = row_ptr[v];
    const int e = row_ptr[v + 1];
    float acc = 0.0f;
    int i = b;
    for (; i + 4 <= e; i += 4) {  // unroll x4: 4 independent gathers in flight
      const int s0 = col[i], s1 = col[i + 1], s2 = col[i + 2], s3 = col[i + 3];
      const float v0 = xin[(size_t)s0 * D + lane];
      const float v1 = xin[(size_t)s1 * D + lane];
      const float v2 = xin[(size_t)s2 * D + lane];
      const float v3 = xin[(size_t)s3 * D + lane];
      acc += (v0 + v1) + (v2 + v3);
    }
    for (; i < e; ++i) acc += xin[(size_t)col[i] * D + lane];
    const float inv = 1.0f / fmaxf((float)(e - b), 1.0f);
    float val = acc * inv;
    if (FINAL) val += radd[(size_t)v * D + lane];
    outbuf[(size_t)v * D + lane] = val;
  }
}

// ---------------------------------------------------------------------------
// Register-tiled fp32 GEMM: C[50000 x 128] = A[50000 x 128] @ W[128 x 128].
// MODE 0 (layer 1): A = [mean1 | x], W = [Wl1 ; Wr1], out = relu(C+b) -> O0[N,128]
// MODE 1 (layer 2): A = h, W = [Wl2 | Wr2],
//                   O0[N,64] = C[:,0:64] (p); O1[N,64] = C[:,64:128] + b (r)
// ROUND-4 LESSON: do NOT unroll the outer ck loop (VGPR blowout -> scratch
// spill, 2.2 GB/dispatch, 15x slowdown). unroll 1 + 3 blocks/CU bound.
template <int MODE>
__global__ __launch_bounds__(256, 3) void gemm128(const float* __restrict__ A0,
                                                  const float* __restrict__ A1,
                                                  const float* __restrict__ W0,
                                                  const float* __restrict__ W1,
                                                  const float* __restrict__ bias,
                                                  float* __restrict__ O0,
                                                  float* __restrict__ O1) {
  constexpr int SAS = 36;  // sA row stride (pad 32->36: rows land on distinct banks)
  __shared__ float sA[64][SAS];
  __shared__ float sW[32][128];
  const int row0 = blockIdx.x * 64;
  const int tid = threadIdx.x;
  const int rowgrp = tid >> 4;   // 0..15
  const int colgrp = tid & 15;   // 0..15
  const int r0 = rowgrp * 4;
  const int j0 = colgrp * 4;

  float accA[4][4];  // cols j0..j0+3
  float accB[4][4];  // cols 64+j0..64+j0+3
#pragma unroll
  for (int r = 0; r < 4; ++r)
#pragma unroll
    for (int c = 0; c < 4; ++c) { accA[r][c] = 0.0f; accB[r][c] = 0.0f; }

#pragma unroll 1   // keep ONE copy of the body (see round-4 lesson above)
  for (int ck = 0; ck < 4; ++ck) {
    // --- stage sA: 64 rows x 32 k ---
#pragma unroll
    for (int v = 0; v < 2; ++v) {
      const int vid = v * 256 + tid;       // 0..511
      const int rr = vid >> 3;             // 0..63
      const int kq = (vid & 7) * 4;        // 0,4,...,28
      const int grow = row0 + rr;
      float4 val = make_float4(0.f, 0.f, 0.f, 0.f);
      if (grow < NNODES) {
        if (MODE == 0) {
          const float* src = (ck < 2) ? A0 : A1;
          const int kk = (ck & 1) * 32 + kq;
          val = *(const float4*)&src[(size_t)grow * 64 + kk];
        } else {
          val = *(const float4*)&A0[(size_t)grow * 128 + ck * 32 + kq];
        }
      }
      *(float4*)&sA[rr][kq] = val;
    }
    // --- stage sW: 32 k x 128 j ---
#pragma unroll
    for (int v = 0; v < 4; ++v) {
      const int vid = v * 256 + tid;       // 0..1023
      const int kk = vid >> 5;             // 0..31
      const int jq = (vid & 31) * 4;       // 0,4,...,124
      float4 w;
      if (MODE == 0) {
        const float* src = (ck < 2) ? W0 : W1;
        const int krel = (ck & 1) * 32 + kk;
        w = *(const float4*)&src[(size_t)krel * 128 + jq];
      } else {
        const int kg = ck * 32 + kk;
        const float* src = (jq < 64) ? W0 : W1;
        const int jrel = (jq < 64) ? jq : jq - 64;
        w = *(const float4*)&src[(size_t)kg * 64 + jrel];
      }
      *(float4*)&sW[kk][jq] = w;
    }
    __syncthreads();
    // --- compute: 32 k's, 128 FMA per 4-k group per thread ---
#pragma unroll
    for (int k4 = 0; k4 < 8; ++k4) {
      float4 a[4];
#pragma unroll
      for (int r = 0; r < 4; ++r) a[r] = *(const float4*)&sA[r0 + r][k4 * 4];
#pragma unroll
      for (int ki = 0; ki < 4; ++ki) {
        const float4 wlo = *(const float4*)&sW[k4 * 4 + ki][j0];
        const float4 whi = *(const float4*)&sW[k4 * 4 + ki][64 + j0];
#pragma unroll
        for (int r = 0; r < 4; ++r) {
          const float av = (ki == 0) ? a[r].x : (ki == 1) ? a[r].y
                         : (ki == 2) ? a[r].z : a[r].w;
          accA[r][0] = fmaf(av, wlo.x, accA[r][0]);
          accA[r][1] = fmaf(av, wlo.y, accA[r][1]);
          accA[r][2] = fmaf(av, wlo.z, accA[r][2]);
          accA[r][3] = fmaf(av, wlo.w, accA[r][3]);
          accB[r][0] = fmaf(av, whi.x, accB[r][0]);
          accB[r][1] = fmaf(av, whi.y, accB[r][1]);
          accB[r][2] = fmaf(av, whi.z, accB[r][2]);
          accB[r][3] = fmaf(av, whi.w, accB[r][3]);
        }
      }
    }
    __syncthreads();
  }

  // --- epilogue ---
  float4 blo = make_float4(0.f, 0.f, 0.f, 0.f);
  float4 bhi;
  if (MODE == 0) {
    blo = *(const float4*)&bias[j0];
    bhi = *(const float4*)&bias[64 + j0];
  } else {
    bhi = *(const float4*)&bias[j0];  // bias applies to r (upper half)
  }
#pragma unroll
  for (int r = 0; r < 4; ++r) {
    const int grow = row0 + r0 + r;
    if (grow >= NNODES) continue;
    float4 lo = make_float4(accA[r][0] + blo.x, accA[r][1] + blo.y,
                            accA[r][2] + blo.z, accA[r][3] + blo.w);
    float4 hi = make_float4(accB[r][0] + bhi.x, accB[r][1] + bhi.y,
                            accB[r][2] + bhi.z, accB[r][3] + bhi.w);
    if (MODE == 0) {
      lo.x = fmaxf(lo.x, 0.f); lo.y = fmaxf(lo.y, 0.f);
      lo.z = fmaxf(lo.z, 0.f); lo.w = fmaxf(lo.w, 0.f);
      hi.x = fmaxf(hi.x, 0.f); hi.y = fmaxf(hi.y, 0.f);
      hi.z = fmaxf(hi.z, 0.f); hi.w = fmaxf(hi.w, 0.f);
      *(float4*)&O0[(size_t)grow * 128 + j0] = lo;
      *(float4*)&O0[(size_t)grow * 128 + 64 + j0] = hi;
    } else {
      *(float4*)&O0[(size_t)grow * 64 + j0] = lo;   // p (no bias; blo==0)
      *(float4*)&O1[(size_t)grow * 64 + j0] = hi;   // r (+bl2)
    }
  }
}

}  // namespace

extern "C" void kernel_launch(void* const* d_in, const int* in_sizes, int n_in,
                              void* d_out, int out_size, void* d_ws, size_t ws_size,
                              hipStream_t stream) {
  const float* x   = (const float*)d_in[0];
  const void*  ei  = d_in[1];  // edge_index, int32 or int64 (detected at runtime)
  const float* Wl1 = (const float*)d_in[2];
  const float* bl1 = (const float*)d_in[3];
  const float* Wr1 = (const float*)d_in[4];
  const float* Wl2 = (const float*)d_in[5];
  const float* bl2 = (const float*)d_in[6];
  const float* Wr2 = (const float*)d_in[7];
  float* out = (float*)d_out;

  // Workspace layout (bytes):
  //   flag    [1]          int32 @ 0          (256)
  //   blkhist [NBUCK*SB]   int32 @ 256        (100,096 pad->100,352)
  //   offs    [NBUCK*SB]   int32 @ 100,608    (100,096 pad->100,352)
  //   bcount  [NBUCK]      int32 @ 200,960    (2,048)
  //   bprefix [NBUCK]      int32 @ 203,008    (2,048)
  //   row_ptr [N+1]        int32 @ 205,056    (200,064 pad->200,192)
  //   col     [E]          int32 @ 405,248    (3,200,000)
  //   ebuf    [NBUCK*BCAP] u32   @ 3,605,248  (4,804,608)
  //   mean1   [N,64]       f32   @ 8,409,856  (12,800,000)  -- reused as r
  //   h       [N,128]      f32   @ 21,209,856 (25,600,000)
  //   p       [N,64]       f32   @ 46,809,856 (12,800,000)
  // total: 59,609,856 bytes. No memsets needed: every buffer is fully
  // written before it is read.
  char* ws = (char*)d_ws;
  int*          flag    = (int*)(ws + 0);
  int*          blkhist = (int*)(ws + 256);
  int*          offs    = (int*)(ws + 100608);
  int*          bcount  = (int*)(ws + 200960);
  int*          bprefix = (int*)(ws + 203008);
  int*          row_ptr = (int*)(ws + 205056);
  int*          col     = (int*)(ws + 405248);
  unsigned int* ebuf    = (unsigned int*)(ws + 3605248);
  float*        mean1   = (float*)(ws + 8409856);
  float*        h       = (float*)(ws + 21209856);
  float*        p       = (float*)(ws + 46809856);
  float*        r       = mean1;  // safe: mean1's last read (gemm128<0>) precedes gemm128<1>'s write

  // CSR build: histogram -> per-bucket offsets -> bucketed scatter ->
  // in-bucket sort + row_ptr emit. Zero global atomics, zero memsets.
  detect_idx64<<<1, 256, 0, stream>>>((const unsigned int*)ei, flag);
  hist_pass<<<SB, 512, 0, stream>>>(ei, flag, blkhist);
  col_scan<<<NBUCK, 64, 0, stream>>>(blkhist, offs, bcount);
  bucket_prefix<<<1, 512, 0, stream>>>(bcount, bprefix);
  scatter_pass<<<SB, 512, 0, stream>>>(ei, flag, offs, ebuf);
  csr_emit2<<<NBUCK, 256, 0, stream>>>(ebuf, bcount, bprefix, row_ptr, col);

  constexpr int GEMM_BLOCKS = (NNODES + 63) / 64;  // 782

  // Layer 1: mean-aggregate x (node-parallel gather), then fused linear+relu
  seg_mean<DIN, false><<<12500, 256, 0, stream>>>(x, row_ptr, col, nullptr, mean1);
  gemm128<0><<<GEMM_BLOCKS, 256, 0, stream>>>(mean1, x, Wl1, Wr1, bl1, h, nullptr);

  // Layer 2: project first (mean commutes with linear), then gather + fused add
  gemm128<1><<<GEMM_BLOCKS, 256, 0, stream>>>(h, nullptr, Wl2, Wr2, bl2, p, r);
  seg_mean<DOUT, true><<<12500, 256, 0, stream>>>(p, row_ptr, col, r, out);
}

// Round 9
// 172.435 us; speedup vs baseline: 4.6829x; 1.0346x over previous
//
#include <hip/hip_runtime.h>

namespace {

constexpr int NNODES = 50000;
constexpr int NEDGES = 800000;
constexpr int NBUCK  = (NNODES + 127) / 128;  // 391 buckets of 128 dst nodes
constexpr int BCAP   = 3072;                  // bucket capacity: mean 2048, ~22 sigma slack
constexpr int SB     = 64;                    // scatter/hist blocks
constexpr int CHUNK  = NEDGES / SB;           // 12500 edges per block (exact)

// ROUND-6 LESSON: per-address global atomic ~140ns serialized -> never >1K
// ops/address (bucket_scatter: 2048/address = 287us).
// ROUND-7 LESSON: aggregation must be node-parallel (50K waves, seg_mean),
// never bucket-parallel (391 blocks = 1.5 blocks/CU, latency-starved, 363us).
// ROUND-8: gathers go bf16 (halve bytes/row + better L2 residency), fp32 accum.

static __device__ __forceinline__ unsigned short f2bf(float f) {
  unsigned u = __float_as_uint(f);
  u += 0x7FFFu + ((u >> 16) & 1u);   // round-to-nearest-even
  return (unsigned short)(u >> 16);
}
static __device__ __forceinline__ float bf2f(unsigned short b) {
  return __uint_as_float((unsigned)b << 16);
}

// In-block int64/int32 detection: odd 32-bit words of the first 4KB are the
// hi-halves of src values (< 50000) for int64 -> all zero; for int32 they are
// random src values -> ~surely nonzero. 512 threads sample one word each.
static __device__ __forceinline__ int detect_is64_block(const void* raw, int* s_tmp) {
  if (threadIdx.x == 0) *s_tmp = 0;
  __syncthreads();
  const unsigned int* w = (const unsigned int*)raw;
  const int nz = (w[1 + 2 * (int)threadIdx.x] != 0u) ? 1 : 0;
  if (nz) atomicOr(s_tmp, 1);
  __syncthreads();
  return (*s_tmp == 0) ? 1 : 0;
}

// x (fp32, [N,64]) -> bf16 copy for the layer-1 gather.
__global__ __launch_bounds__(256) void x_to_bf16(const float* __restrict__ xin,
                                                 unsigned short* __restrict__ xb) {
  const int total4 = NNODES * 64 / 4;  // 800000 float4 groups
  const int stride = gridDim.x * blockDim.x;
  for (int t = blockIdx.x * blockDim.x + threadIdx.x; t < total4; t += stride) {
    const float4 v = ((const float4*)xin)[t];
    ushort4 o;
    o.x = f2bf(v.x); o.y = f2bf(v.y); o.z = f2bf(v.z); o.w = f2bf(v.w);
    ((ushort4*)xb)[t] = o;
  }
}

// Phase 1: per-block LDS histogram over buckets -> blkhist[bucket*SB + block].
__global__ __launch_bounds__(512) void hist_pass(const void* __restrict__ raw,
                                                 int* __restrict__ blkhist) {
  __shared__ int hist[NBUCK];
  __shared__ int s_tmp;
  const int is64 = detect_is64_block(raw, &s_tmp);
  for (int i = threadIdx.x; i < NBUCK; i += 512) hist[i] = 0;
  __syncthreads();
  const int b = blockIdx.x;
  const int beg = b * CHUNK, end = beg + CHUNK;
  for (int e = beg + (int)threadIdx.x; e < end; e += 512) {
    const int d = is64 ? (int)((const long long*)raw)[NEDGES + e]
                       : ((const int*)raw)[NEDGES + e];
    atomicAdd(&hist[d >> 7], 1);
  }
  __syncthreads();
  for (int i = threadIdx.x; i < NBUCK; i += 512) blkhist[i * SB + b] = hist[i];
}

// Phase 2: per-bucket exclusive scan over the SB block-counts -> exact write
// offsets into the bucket's fixed-capacity region; also bucket totals.
__global__ __launch_bounds__(64) void col_scan(const int* __restrict__ blkhist,
                                               int* __restrict__ offs,
                                               int* __restrict__ bcount) {
  const int bk = blockIdx.x;
  const int t = threadIdx.x;
  const int c = blkhist[bk * SB + t];
  int s = c;
#pragma unroll
  for (int off = 1; off < 64; off <<= 1) {
    const int u = __shfl_up(s, off, 64);
    if (t >= off) s += u;
  }
  offs[bk * SB + t] = bk * BCAP + (s - c);
  if (t == 63) bcount[bk] = s;
}

// Exclusive scan of bcount[NBUCK] -> bprefix (bucket base in final col-space).
__global__ __launch_bounds__(512) void bucket_prefix(const int* __restrict__ bcount,
                                                     int* __restrict__ bprefix) {
  __shared__ int sh[512];
  const int t = threadIdx.x;
  const int v = (t < NBUCK) ? bcount[t] : 0;
  sh[t] = v;
  __syncthreads();
#pragma unroll
  for (int off = 1; off < 512; off <<= 1) {
    const int val = sh[t];
    const int add = (t >= off) ? sh[t - off] : 0;
    __syncthreads();
    sh[t] = val + add;
    __syncthreads();
  }
  if (t < NBUCK) bprefix[t] = sh[t] - v;
}

// Phase 3: place packed edges (dst<<16 | src, both < 2^16) into bucket
// regions. Per-(block,bucket) runs are contiguous -> good write-line
// utilization; LDS cursors only, zero global atomics.
__global__ __launch_bounds__(512) void scatter_pass(const void* __restrict__ raw,
                                                    const int* __restrict__ offs,
                                                    unsigned int* __restrict__ ebuf) {
  __shared__ int loff[NBUCK];
  __shared__ int lcur[NBUCK];
  __shared__ int s_tmp;
  const int is64 = detect_is64_block(raw, &s_tmp);
  const int b = blockIdx.x;
  for (int i = threadIdx.x; i < NBUCK; i += 512) {
    loff[i] = offs[i * SB + b];
    lcur[i] = 0;
  }
  __syncthreads();
  const int beg = b * CHUNK, end = beg + CHUNK;
  for (int e = beg + (int)threadIdx.x; e < end; e += 512) {
    int s, d;
    if (is64) {
      const long long* p = (const long long*)raw;
      s = (int)p[e];
      d = (int)p[NEDGES + e];
    } else {
      const int* p = (const int*)raw;
      s = p[e];
      d = p[NEDGES + e];
    }
    const int bk = d >> 7;
    const unsigned int val = ((unsigned int)d << 16) | (unsigned int)s;
    const int lr = atomicAdd(&lcur[bk], 1);
    ebuf[loff[bk] + lr] = val;
  }
}

// Phase 4: one block per bucket. Sort the bucket's edges into final CSR
// order via LDS count+scan+place; ALSO emits row_ptr. Edges cached in
// registers (<=12/thread, static indexing). col writes land in one
// contiguous ~8KB region -> full write-line utilization.
__global__ __launch_bounds__(256) void csr_emit2(const unsigned int* __restrict__ ebuf,
                                                 const int* __restrict__ bcount,
                                                 const int* __restrict__ bprefix,
                                                 int* __restrict__ row_ptr,
                                                 int* __restrict__ col) {
  const int bk = blockIdx.x;
  const int base = bk * 128;
  const int nloc = min(128, NNODES - base);
  const int cnt = bcount[bk];          // <= BCAP = 3072 = 12*256
  const int bbase = bprefix[bk];
  const unsigned int* eb = ebuf + (size_t)bk * BCAP;

  __shared__ int dcnt[128];
  __shared__ int loff[128];
  __shared__ int lcur[128];
  if (threadIdx.x < 128) dcnt[threadIdx.x] = 0;
  __syncthreads();

  // pass A: cache edges + per-node counts
  unsigned int vals[12];
  int m = 0;
#pragma unroll
  for (int k = 0; k < 12; ++k) {
    const int e = (int)threadIdx.x + k * 256;
    if (e < cnt) {
      vals[k] = eb[e];
      atomicAdd(&dcnt[(vals[k] >> 16) & 127u], 1);
      m = k + 1;
    }
  }
  __syncthreads();

  // exclusive scan of dcnt[0..127] (Hillis-Steele in LDS)
  if (threadIdx.x < 128) loff[threadIdx.x] = dcnt[threadIdx.x];
  __syncthreads();
#pragma unroll
  for (int off = 1; off < 128; off <<= 1) {
    int add = 0;
    if (threadIdx.x < 128 && (int)threadIdx.x >= off) add = loff[threadIdx.x - off];
    __syncthreads();
    if (threadIdx.x < 128) loff[threadIdx.x] += add;
    __syncthreads();
  }
  if (threadIdx.x < 128) {
    const int excl = loff[threadIdx.x] - dcnt[threadIdx.x];
    loff[threadIdx.x] = excl;
    lcur[threadIdx.x] = 0;
    if ((int)threadIdx.x < nloc) row_ptr[base + threadIdx.x] = bbase + excl;
  }
  if (bk == NBUCK - 1 && threadIdx.x == 0) row_ptr[NNODES] = NEDGES;
  __syncthreads();

  // pass B: place
#pragma unroll
  for (int k = 0; k < 12; ++k) {
    if (k < m) {
      const int loc = (int)((vals[k] >> 16) & 127u);
      const int slot = bbase + loff[loc] + atomicAdd(&lcur[loc], 1);
      col[slot] = (int)(vals[k] & 0xFFFFu);
    }
  }
}

// Segment mean via gather: one wave (64 lanes == 64 channels) per node.
// Gathers bf16 rows (128B each), accumulates fp32.
template <bool FINAL>
__global__ __launch_bounds__(256) void seg_mean_bf(const unsigned short* __restrict__ xb,
                                                   const int* __restrict__ row_ptr,
                                                   const int* __restrict__ col,
                                                   const float* __restrict__ radd,
                                                   float* __restrict__ outbuf) {
  const int lane = threadIdx.x & 63;
  const int wid = (blockIdx.x * blockDim.x + threadIdx.x) >> 6;
  const int nw = (gridDim.x * blockDim.x) >> 6;
  for (int v = wid; v < NNODES; v += nw) {
    const int b = row_ptr[v];
    const int e = row_ptr[v + 1];
    float acc = 0.0f;
    int i = b;
    for (; i + 4 <= e; i += 4) {  // 4 independent gathers in flight
      const int s0 = col[i], s1 = col[i + 1], s2 = col[i + 2], s3 = col[i + 3];
      const float v0 = bf2f(xb[(size_t)s0 * 64 + lane]);
      const float v1 = bf2f(xb[(size_t)s1 * 64 + lane]);
      const float v2 = bf2f(xb[(size_t)s2 * 64 + lane]);
      const float v3 = bf2f(xb[(size_t)s3 * 64 + lane]);
      acc += (v0 + v1) + (v2 + v3);
    }
    for (; i < e; ++i) acc += bf2f(xb[(size_t)col[i] * 64 + lane]);
    const float inv = 1.0f / fmaxf((float)(e - b), 1.0f);
    float val = acc * inv;
    if (FINAL) val += radd[(size_t)v * 64 + lane];
    outbuf[(size_t)v * 64 + lane] = val;
  }
}

// ---------------------------------------------------------------------------
// Register-tiled fp32 GEMM: C[50000 x 128] = A[50000 x 128] @ W[128 x 128].
// MODE 0 (layer 1): A = [mean1 | x], W = [Wl1 ; Wr1], out = relu(C+b) -> O0[N,128]
// MODE 1 (layer 2): A = h, W = [Wl2 | Wr2],
//                   PB[N,64](bf16) = C[:,0:64] (p); O1[N,64] = C[:,64:128] + b (r)
// ROUND-4 LESSON: do NOT unroll the outer ck loop (VGPR blowout -> scratch
// spill, 2.2 GB/dispatch, 15x slowdown). unroll 1 + 3 blocks/CU bound.
template <int MODE>
__global__ __launch_bounds__(256, 3) void gemm128(const float* __restrict__ A0,
                                                  const float* __restrict__ A1,
                                                  const float* __restrict__ W0,
                                                  const float* __restrict__ W1,
                                                  const float* __restrict__ bias,
                                                  float* __restrict__ O0,
                                                  float* __restrict__ O1,
                                                  unsigned short* __restrict__ PB) {
  constexpr int SAS = 36;  // sA row stride (pad 32->36: rows land on distinct banks)
  __shared__ float sA[64][SAS];
  __shared__ float sW[32][128];
  const int row0 = blockIdx.x * 64;
  const int tid = threadIdx.x;
  const int rowgrp = tid >> 4;   // 0..15
  const int colgrp = tid & 15;   // 0..15
  const int r0 = rowgrp * 4;
  const int j0 = colgrp * 4;

  float accA[4][4];  // cols j0..j0+3
  float accB[4][4];  // cols 64+j0..64+j0+3
#pragma unroll
  for (int r = 0; r < 4; ++r)
#pragma unroll
    for (int c = 0; c < 4; ++c) { accA[r][c] = 0.0f; accB[r][c] = 0.0f; }

#pragma unroll 1   // keep ONE copy of the body (see round-4 lesson above)
  for (int ck = 0; ck < 4; ++ck) {
    // --- stage sA: 64 rows x 32 k ---
#pragma unroll
    for (int v = 0; v < 2; ++v) {
      const int vid = v * 256 + tid;       // 0..511
      const int rr = vid >> 3;             // 0..63
      const int kq = (vid & 7) * 4;        // 0,4,...,28
      const int grow = row0 + rr;
      float4 val = make_float4(0.f, 0.f, 0.f, 0.f);
      if (grow < NNODES) {
        if (MODE == 0) {
          const float* src = (ck < 2) ? A0 : A1;
          const int kk = (ck & 1) * 32 + kq;
          val = *(const float4*)&src[(size_t)grow * 64 + kk];
        } else {
          val = *(const float4*)&A0[(size_t)grow * 128 + ck * 32 + kq];
        }
      }
      *(float4*)&sA[rr][kq] = val;
    }
    // --- stage sW: 32 k x 128 j ---
#pragma unroll
    for (int v = 0; v < 4; ++v) {
      const int vid = v * 256 + tid;       // 0..1023
      const int kk = vid >> 5;             // 0..31
      const int jq = (vid & 31) * 4;       // 0,4,...,124
      float4 w;
      if (MODE == 0) {
        const float* src = (ck < 2) ? W0 : W1;
        const int krel = (ck & 1) * 32 + kk;
        w = *(const float4*)&src[(size_t)krel * 128 + jq];
      } else {
        const int kg = ck * 32 + kk;
        const float* src = (jq < 64) ? W0 : W1;
        const int jrel = (jq < 64) ? jq : jq - 64;
        w = *(const float4*)&src[(size_t)kg * 64 + jrel];
      }
      *(float4*)&sW[kk][jq] = w;
    }
    __syncthreads();
    // --- compute: 32 k's, 128 FMA per 4-k group per thread ---
#pragma unroll
    for (int k4 = 0; k4 < 8; ++k4) {
      float4 a[4];
#pragma unroll
      for (int r = 0; r < 4; ++r) a[r] = *(const float4*)&sA[r0 + r][k4 * 4];
#pragma unroll
      for (int ki = 0; ki < 4; ++ki) {
        const float4 wlo = *(const float4*)&sW[k4 * 4 + ki][j0];
        const float4 whi = *(const float4*)&sW[k4 * 4 + ki][64 + j0];
#pragma unroll
        for (int r = 0; r < 4; ++r) {
          const float av = (ki == 0) ? a[r].x : (ki == 1) ? a[r].y
                         : (ki == 2) ? a[r].z : a[r].w;
          accA[r][0] = fmaf(av, wlo.x, accA[r][0]);
          accA[r][1] = fmaf(av, wlo.y, accA[r][1]);
          accA[r][2] = fmaf(av, wlo.z, accA[r][2]);
          accA[r][3] = fmaf(av, wlo.w, accA[r][3]);
          accB[r][0] = fmaf(av, whi.x, accB[r][0]);
          accB[r][1] = fmaf(av, whi.y, accB[r][1]);
          accB[r][2] = fmaf(av, whi.z, accB[r][2]);
          accB[r][3] = fmaf(av, whi.w, accB[r][3]);
        }
      }
    }
    __syncthreads();
  }

  // --- epilogue ---
  float4 blo = make_float4(0.f, 0.f, 0.f, 0.f);
  float4 bhi;
  if (MODE == 0) {
    blo = *(const float4*)&bias[j0];
    bhi = *(const float4*)&bias[64 + j0];
  } else {
    bhi = *(const float4*)&bias[j0];  // bias applies to r (upper half)
  }
#pragma unroll
  for (int r = 0; r < 4; ++r) {
    const int grow = row0 + r0 + r;
    if (grow >= NNODES) continue;
    float4 lo = make_float4(accA[r][0] + blo.x, accA[r][1] + blo.y,
                            accA[r][2] + blo.z, accA[r][3] + blo.w);
    float4 hi = make_float4(accB[r][0] + bhi.x, accB[r][1] + bhi.y,
                            accB[r][2] + bhi.z, accB[r][3] + bhi.w);
    if (MODE == 0) {
      lo.x = fmaxf(lo.x, 0.f); lo.y = fmaxf(lo.y, 0.f);
      lo.z = fmaxf(lo.z, 0.f); lo.w = fmaxf(lo.w, 0.f);
      hi.x = fmaxf(hi.x, 0.f); hi.y = fmaxf(hi.y, 0.f);
      hi.z = fmaxf(hi.z, 0.f); hi.w = fmaxf(hi.w, 0.f);
      *(float4*)&O0[(size_t)grow * 128 + j0] = lo;
      *(float4*)&O0[(size_t)grow * 128 + 64 + j0] = hi;
    } else {
      ushort4 ob;
      ob.x = f2bf(lo.x); ob.y = f2bf(lo.y); ob.z = f2bf(lo.z); ob.w = f2bf(lo.w);
      *(ushort4*)&PB[(size_t)grow * 64 + j0] = ob;  // p as bf16 (gather operand)
      *(float4*)&O1[(size_t)grow * 64 + j0] = hi;   // r (+bl2), fp32
    }
  }
}

}  // namespace

extern "C" void kernel_launch(void* const* d_in, const int* in_sizes, int n_in,
                              void* d_out, int out_size, void* d_ws, size_t ws_size,
                              hipStream_t stream) {
  const float* x   = (const float*)d_in[0];
  const void*  ei  = d_in[1];  // edge_index, int32 or int64 (detected in-block)
  const float* Wl1 = (const float*)d_in[2];
  const float* bl1 = (const float*)d_in[3];
  const float* Wr1 = (const float*)d_in[4];
  const float* Wl2 = (const float*)d_in[5];
  const float* bl2 = (const float*)d_in[6];
  const float* Wr2 = (const float*)d_in[7];
  float* out = (float*)d_out;

  // Workspace layout (bytes):
  //   blkhist [NBUCK*SB]   int32 @ 0          (100,096 pad->100,352)
  //   offs    [NBUCK*SB]   int32 @ 100,352    (100,096 pad->100,352)
  //   bcount  [NBUCK]      int32 @ 200,704    (2,048)
  //   bprefix [NBUCK]      int32 @ 202,752    (2,048)
  //   row_ptr [N+1]        int32 @ 204,800    (200,064 pad->200,192)
  //   col     [E]          int32 @ 404,992    (3,200,000)
  //   ebuf    [NBUCK*BCAP] u32   @ 3,604,992  (4,804,608)
  //   xb      [N,64]       bf16  @ 8,409,600  (6,400,000)
  //   pb      [N,64]       bf16  @ 14,809,600 (6,400,000)
  //   mean1   [N,64]       f32   @ 21,209,600 (12,800,000)  -- reused as r
  //   h       [N,128]      f32   @ 34,009,600 (25,600,000)
  // total: 59,609,600 bytes. No memsets: every buffer fully written before read.
  char* ws = (char*)d_ws;
  int*            blkhist = (int*)(ws + 0);
  int*            offs    = (int*)(ws + 100352);
  int*            bcount  = (int*)(ws + 200704);
  int*            bprefix = (int*)(ws + 202752);
  int*            row_ptr = (int*)(ws + 204800);
  int*            col     = (int*)(ws + 404992);
  unsigned int*   ebuf    = (unsigned int*)(ws + 3604992);
  unsigned short* xb      = (unsigned short*)(ws + 8409600);
  unsigned short* pb      = (unsigned short*)(ws + 14809600);
  float*          mean1   = (float*)(ws + 21209600);
  float*          h       = (float*)(ws + 34009600);
  float*          r       = mean1;  // safe: mean1's last read (gemm128<0>) precedes gemm128<1>'s write

  // bf16 copy of x for the layer-1 gather (independent; runs while CSR builds)
  x_to_bf16<<<1024, 256, 0, stream>>>(x, xb);

  // CSR build: histogram -> per-bucket offsets -> bucketed scatter ->
  // in-bucket sort + row_ptr emit. Zero global atomics, zero memsets.
  hist_pass<<<SB, 512, 0, stream>>>(ei, blkhist);
  col_scan<<<NBUCK, 64, 0, stream>>>(blkhist, offs, bcount);
  bucket_prefix<<<1, 512, 0, stream>>>(bcount, bprefix);
  scatter_pass<<<SB, 512, 0, stream>>>(ei, offs, ebuf);
  csr_emit2<<<NBUCK, 256, 0, stream>>>(ebuf, bcount, bprefix, row_ptr, col);

  constexpr int GEMM_BLOCKS = (NNODES + 63) / 64;  // 782

  // Layer 1: mean-aggregate x (node-parallel bf16 gather), then fused linear+relu
  seg_mean_bf<false><<<12500, 256, 0, stream>>>(xb, row_ptr, col, nullptr, mean1);
  gemm128<0><<<GEMM_BLOCKS, 256, 0, stream>>>(mean1, x, Wl1, Wr1, bl1, h, nullptr, nullptr);

  // Layer 2: project first (mean commutes with linear; p emitted as bf16),
  // then gather + fused add of r
  gemm128<1><<<GEMM_BLOCKS, 256, 0, stream>>>(h, nullptr, Wl2, Wr2, bl2, nullptr, r, pb);
  seg_mean_bf<true><<<12500, 256, 0, stream>>>(pb, row_ptr, col, r, out);
}

// Round 10
// 163.613 us; speedup vs baseline: 4.9354x; 1.0539x over previous
//
#include <hip/hip_runtime.h>

namespace {

constexpr int NNODES = 50000;
constexpr int NEDGES = 800000;
constexpr int NBUCK  = (NNODES + 127) / 128;  // 391 buckets of 128 dst nodes
constexpr int BCAP   = 3072;                  // bucket capacity: mean 2048, ~22 sigma slack
constexpr int SB     = 64;                    // scatter/hist blocks
constexpr int CHUNK  = NEDGES / SB;           // 12500 edges per block (exact)

// ROUND-6 LESSON: per-address global atomic ~140ns serialized -> never >1K
// ops/address. ROUND-7 LESSON: aggregation must be node-parallel (50K waves),
// never bucket-parallel. ROUND-9 LESSON: seg_mean is latency/issue-bound,
// not byte-bound (bf16 halved bytes, gained only 6us) -> attack instruction
// count (2 edges per load via dword lanes) not bytes.

static __device__ __forceinline__ unsigned short f2bf(float f) {
  unsigned u = __float_as_uint(f);
  u += 0x7FFFu + ((u >> 16) & 1u);   // round-to-nearest-even
  return (unsigned short)(u >> 16);
}

// v_pk_fma_f32: d = a*b + d elementwise on float2 (2 FMA/lane/cycle; the
// scalar fmaf path runs at half the fp32 peak). op_sel broadcasts one half
// of src0 to both output lanes, avoiding explicit broadcast movs:
//   lo: both lanes use a.x   hi: both lanes use a.y
static __device__ __forceinline__ void pk_fma_lo(float2& d, const float2 a, const float2 b) {
  asm("v_pk_fma_f32 %0, %1, %2, %0 op_sel:[0,0,0] op_sel_hi:[0,1,1]"
      : "+v"(d) : "v"(a), "v"(b));
}
static __device__ __forceinline__ void pk_fma_hi(float2& d, const float2 a, const float2 b) {
  asm("v_pk_fma_f32 %0, %1, %2, %0 op_sel:[1,0,0] op_sel_hi:[1,1,1]"
      : "+v"(d) : "v"(a), "v"(b));
}

// In-block int64/int32 detection: odd 32-bit words of the first 4KB are the
// hi-halves of src values (< 50000) for int64 -> all zero; for int32 they are
// random src values -> ~surely nonzero.
static __device__ __forceinline__ int detect_is64_block(const void* raw, int* s_tmp) {
  if (threadIdx.x == 0) *s_tmp = 0;
  __syncthreads();
  const unsigned int* w = (const unsigned int*)raw;
  const int nz = (w[1 + 2 * (int)threadIdx.x] != 0u) ? 1 : 0;
  if (nz) atomicOr(s_tmp, 1);
  __syncthreads();
  return (*s_tmp == 0) ? 1 : 0;
}

// x (fp32, [N,64]) -> bf16 copy for the layer-1 gather.
__global__ __launch_bounds__(256) void x_to_bf16(const float* __restrict__ xin,
                                                 unsigned short* __restrict__ xb) {
  const int total4 = NNODES * 64 / 4;  // 800000 float4 groups
  const int stride = gridDim.x * blockDim.x;
  for (int t = blockIdx.x * blockDim.x + threadIdx.x; t < total4; t += stride) {
    const float4 v = ((const float4*)xin)[t];
    ushort4 o;
    o.x = f2bf(v.x); o.y = f2bf(v.y); o.z = f2bf(v.z); o.w = f2bf(v.w);
    ((ushort4*)xb)[t] = o;
  }
}

// Phase 1: per-block LDS histogram over buckets -> blkhist[bucket*SB + block].
__global__ __launch_bounds__(512) void hist_pass(const void* __restrict__ raw,
                                                 int* __restrict__ blkhist) {
  __shared__ int hist[NBUCK];
  __shared__ int s_tmp;
  const int is64 = detect_is64_block(raw, &s_tmp);
  for (int i = threadIdx.x; i < NBUCK; i += 512) hist[i] = 0;
  __syncthreads();
  const int b = blockIdx.x;
  const int beg = b * CHUNK, end = beg + CHUNK;
  for (int e = beg + (int)threadIdx.x; e < end; e += 512) {
    const int d = is64 ? (int)((const long long*)raw)[NEDGES + e]
                       : ((const int*)raw)[NEDGES + e];
    atomicAdd(&hist[d >> 7], 1);
  }
  __syncthreads();
  for (int i = threadIdx.x; i < NBUCK; i += 512) blkhist[i * SB + b] = hist[i];
}

// Phase 2: per-bucket exclusive scan over the SB block-counts.
__global__ __launch_bounds__(64) void col_scan(const int* __restrict__ blkhist,
                                               int* __restrict__ offs,
                                               int* __restrict__ bcount) {
  const int bk = blockIdx.x;
  const int t = threadIdx.x;
  const int c = blkhist[bk * SB + t];
  int s = c;
#pragma unroll
  for (int off = 1; off < 64; off <<= 1) {
    const int u = __shfl_up(s, off, 64);
    if (t >= off) s += u;
  }
  offs[bk * SB + t] = bk * BCAP + (s - c);
  if (t == 63) bcount[bk] = s;
}

// Exclusive scan of bcount[NBUCK] -> bprefix (bucket base in final col-space).
__global__ __launch_bounds__(512) void bucket_prefix(const int* __restrict__ bcount,
                                                     int* __restrict__ bprefix) {
  __shared__ int sh[512];
  const int t = threadIdx.x;
  const int v = (t < NBUCK) ? bcount[t] : 0;
  sh[t] = v;
  __syncthreads();
#pragma unroll
  for (int off = 1; off < 512; off <<= 1) {
    const int val = sh[t];
    const int add = (t >= off) ? sh[t - off] : 0;
    __syncthreads();
    sh[t] = val + add;
    __syncthreads();
  }
  if (t < NBUCK) bprefix[t] = sh[t] - v;
}

// Phase 3: place packed edges (dst<<16 | src) into bucket regions.
__global__ __launch_bounds__(512) void scatter_pass(const void* __restrict__ raw,
                                                    const int* __restrict__ offs,
                                                    unsigned int* __restrict__ ebuf) {
  __shared__ int loff[NBUCK];
  __shared__ int lcur[NBUCK];
  __shared__ int s_tmp;
  const int is64 = detect_is64_block(raw, &s_tmp);
  const int b = blockIdx.x;
  for (int i = threadIdx.x; i < NBUCK; i += 512) {
    loff[i] = offs[i * SB + b];
    lcur[i] = 0;
  }
  __syncthreads();
  const int beg = b * CHUNK, end = beg + CHUNK;
  for (int e = beg + (int)threadIdx.x; e < end; e += 512) {
    int s, d;
    if (is64) {
      const long long* p = (const long long*)raw;
      s = (int)p[e];
      d = (int)p[NEDGES + e];
    } else {
      const int* p = (const int*)raw;
      s = p[e];
      d = p[NEDGES + e];
    }
    const int bk = d >> 7;
    const unsigned int val = ((unsigned int)d << 16) | (unsigned int)s;
    const int lr = atomicAdd(&lcur[bk], 1);
    ebuf[loff[bk] + lr] = val;
  }
}

// Phase 4: one block per bucket; in-bucket sort to CSR order + row_ptr emit.
__global__ __launch_bounds__(256) void csr_emit2(const unsigned int* __restrict__ ebuf,
                                                 const int* __restrict__ bcount,
                                                 const int* __restrict__ bprefix,
                                                 int* __restrict__ row_ptr,
                                                 int* __restrict__ col) {
  const int bk = blockIdx.x;
  const int base = bk * 128;
  const int nloc = min(128, NNODES - base);
  const int cnt = bcount[bk];          // <= BCAP = 3072 = 12*256
  const int bbase = bprefix[bk];
  const unsigned int* eb = ebuf + (size_t)bk * BCAP;

  __shared__ int dcnt[128];
  __shared__ int loff[128];
  __shared__ int lcur[128];
  if (threadIdx.x < 128) dcnt[threadIdx.x] = 0;
  __syncthreads();

  unsigned int vals[12];
  int m = 0;
#pragma unroll
  for (int k = 0; k < 12; ++k) {
    const int e = (int)threadIdx.x + k * 256;
    if (e < cnt) {
      vals[k] = eb[e];
      atomicAdd(&dcnt[(vals[k] >> 16) & 127u], 1);
      m = k + 1;
    }
  }
  __syncthreads();

  if (threadIdx.x < 128) loff[threadIdx.x] = dcnt[threadIdx.x];
  __syncthreads();
#pragma unroll
  for (int off = 1; off < 128; off <<= 1) {
    int add = 0;
    if (threadIdx.x < 128 && (int)threadIdx.x >= off) add = loff[threadIdx.x - off];
    __syncthreads();
    if (threadIdx.x < 128) loff[threadIdx.x] += add;
    __syncthreads();
  }
  if (threadIdx.x < 128) {
    const int excl = loff[threadIdx.x] - dcnt[threadIdx.x];
    loff[threadIdx.x] = excl;
    lcur[threadIdx.x] = 0;
    if ((int)threadIdx.x < nloc) row_ptr[base + threadIdx.x] = bbase + excl;
  }
  if (bk == NBUCK - 1 && threadIdx.x == 0) row_ptr[NNODES] = NEDGES;
  __syncthreads();

#pragma unroll
  for (int k = 0; k < 12; ++k) {
    if (k < m) {
      const int loc = (int)((vals[k] >> 16) & 127u);
      const int slot = bbase + loff[loc] + atomicAdd(&lcur[loc], 1);
      col[slot] = (int)(vals[k] & 0xFFFFu);
    }
  }
}

// Segment mean, 2 edges per load instruction: lane = (edge-slot, channel-pair).
// Lanes 0-31 handle even edges, 32-63 odd edges; each lane loads one dword
// (2 bf16 channels) per edge -> one 64-lane instruction covers 2 full rows.
// Cross-half __shfl_xor(32) combines the two slots. fp32 accumulate.
template <bool FINAL>
__global__ __launch_bounds__(256) void seg_mean_bf(const unsigned int* __restrict__ xb2,
                                                   const int* __restrict__ row_ptr,
                                                   const int* __restrict__ col,
                                                   const float* __restrict__ radd,
                                                   float* __restrict__ outbuf) {
  const int lane = (int)(threadIdx.x & 63);
  const int half = lane >> 5;     // edge slot (0: even edges, 1: odd)
  const int c = lane & 31;        // channel pair (chans 2c, 2c+1)
  const int wid = (blockIdx.x * blockDim.x + threadIdx.x) >> 6;
  const int nw = (gridDim.x * blockDim.x) >> 6;
  for (int v = wid; v < NNODES; v += nw) {
    const int b = row_ptr[v];
    const int e = row_ptr[v + 1];
    float accx = 0.0f, accy = 0.0f;
    int i = b;
    for (; i + 8 <= e; i += 8) {  // 8 edges via 4 dual-edge gathers in flight
      const int s0 = col[i + 0 + half];
      const int s1 = col[i + 2 + half];
      const int s2 = col[i + 4 + half];
      const int s3 = col[i + 6 + half];
      const unsigned int w0 = xb2[(size_t)s0 * 32 + c];
      const unsigned int w1 = xb2[(size_t)s1 * 32 + c];
      const unsigned int w2 = xb2[(size_t)s2 * 32 + c];
      const unsigned int w3 = xb2[(size_t)s3 * 32 + c];
      accx += __uint_as_float(w0 << 16) + __uint_as_float(w1 << 16)
            + __uint_as_float(w2 << 16) + __uint_as_float(w3 << 16);
      accy += __uint_as_float(w0 & 0xFFFF0000u) + __uint_as_float(w1 & 0xFFFF0000u)
            + __uint_as_float(w2 & 0xFFFF0000u) + __uint_as_float(w3 & 0xFFFF0000u);
    }
    for (; i + 2 <= e; i += 2) {  // pair remainder
      const unsigned int w0 = xb2[(size_t)col[i + half] * 32 + c];
      accx += __uint_as_float(w0 << 16);
      accy += __uint_as_float(w0 & 0xFFFF0000u);
    }
    if (i < e && half == 0) {     // odd last edge: slot 0 only
      const unsigned int w0 = xb2[(size_t)col[i] * 32 + c];
      accx += __uint_as_float(w0 << 16);
      accy += __uint_as_float(w0 & 0xFFFF0000u);
    }
    accx += __shfl_xor(accx, 32, 64);
    accy += __shfl_xor(accy, 32, 64);
    if (half == 0) {
      const float inv = 1.0f / fmaxf((float)(e - b), 1.0f);
      float2 res = make_float2(accx * inv, accy * inv);
      const size_t gi = (size_t)v * 32 + c;
      if (FINAL) {
        const float2 ra = ((const float2*)radd)[gi];
        res.x += ra.x; res.y += ra.y;
      }
      ((float2*)outbuf)[gi] = res;
    }
  }
}

// ---------------------------------------------------------------------------
// Register-tiled fp32 GEMM with v_pk_fma_f32 inner loop (2 FMA/lane/cycle):
// C[50000 x 128] = A[50000 x 128] @ W[128 x 128].
// MODE 0 (layer 1): A = [mean1 | x], W = [Wl1 ; Wr1], out = relu(C+b) -> O0[N,128]
// MODE 1 (layer 2): A = h, W = [Wl2 | Wr2],
//                   PB[N,64](bf16) = C[:,0:64] (p); O1[N,64] = C[:,64:128] + b (r)
// ROUND-4 LESSON: do NOT unroll the outer ck loop (VGPR blowout -> scratch
// spill, 2.2 GB/dispatch, 15x slowdown). unroll 1 + 3 blocks/CU bound.
template <int MODE>
__global__ __launch_bounds__(256, 3) void gemm128(const float* __restrict__ A0,
                                                  const float* __restrict__ A1,
                                                  const float* __restrict__ W0,
                                                  const float* __restrict__ W1,
                                                  const float* __restrict__ bias,
                                                  float* __restrict__ O0,
                                                  float* __restrict__ O1,
                                                  unsigned short* __restrict__ PB) {
  constexpr int SAS = 36;  // sA row stride (pad 32->36: rows land on distinct banks)
  __shared__ float sA[64][SAS];
  __shared__ float sW[32][128];
  const int row0 = blockIdx.x * 64;
  const int tid = threadIdx.x;
  const int r0 = (tid >> 4) * 4;
  const int j0 = (tid & 15) * 4;

  // acc pairs: accA2[r][p] = cols (j0+2p, j0+2p+1); accB2: +64.
  float2 accA2[4][2];
  float2 accB2[4][2];
#pragma unroll
  for (int r = 0; r < 4; ++r)
#pragma unroll
    for (int p = 0; p < 2; ++p) {
      accA2[r][p] = make_float2(0.f, 0.f);
      accB2[r][p] = make_float2(0.f, 0.f);
    }

#pragma unroll 1   // keep ONE copy of the body (round-4 lesson)
  for (int ck = 0; ck < 4; ++ck) {
    // --- stage sA: 64 rows x 32 k ---
#pragma unroll
    for (int v = 0; v < 2; ++v) {
      const int vid = v * 256 + tid;
      const int rr = vid >> 3;
      const int kq = (vid & 7) * 4;
      const int grow = row0 + rr;
      float4 val = make_float4(0.f, 0.f, 0.f, 0.f);
      if (grow < NNODES) {
        if (MODE == 0) {
          const float* src = (ck < 2) ? A0 : A1;
          const int kk = (ck & 1) * 32 + kq;
          val = *(const float4*)&src[(size_t)grow * 64 + kk];
        } else {
          val = *(const float4*)&A0[(size_t)grow * 128 + ck * 32 + kq];
        }
      }
      *(float4*)&sA[rr][kq] = val;
    }
    // --- stage sW: 32 k x 128 j ---
#pragma unroll
    for (int v = 0; v < 4; ++v) {
      const int vid = v * 256 + tid;
      const int kk = vid >> 5;
      const int jq = (vid & 31) * 4;
      float4 w;
      if (MODE == 0) {
        const float* src = (ck < 2) ? W0 : W1;
        const int krel = (ck & 1) * 32 + kk;
        w = *(const float4*)&src[(size_t)krel * 128 + jq];
      } else {
        const int kg = ck * 32 + kk;
        const float* src = (jq < 64) ? W0 : W1;
        const int jrel = (jq < 64) ? jq : jq - 64;
        w = *(const float4*)&src[(size_t)kg * 64 + jrel];
      }
      *(float4*)&sW[kk][jq] = w;
    }
    __syncthreads();
    // --- compute: 32 k's; per k-pair use op_sel lo/hi broadcast of A ---
#pragma unroll
    for (int k4 = 0; k4 < 8; ++k4) {
      float4 a[4];
#pragma unroll
      for (int r = 0; r < 4; ++r) a[r] = *(const float4*)&sA[r0 + r][k4 * 4];
#pragma unroll
      for (int kp = 0; kp < 2; ++kp) {
        const int k_even = k4 * 4 + kp * 2;
        const float4 wlo0 = *(const float4*)&sW[k_even][j0];
        const float4 whi0 = *(const float4*)&sW[k_even][64 + j0];
        const float4 wlo1 = *(const float4*)&sW[k_even + 1][j0];
        const float4 whi1 = *(const float4*)&sW[k_even + 1][64 + j0];
#pragma unroll
        for (int r = 0; r < 4; ++r) {
          const float2 ap = (kp == 0) ? make_float2(a[r].x, a[r].y)
                                      : make_float2(a[r].z, a[r].w);
          // k = k_even: A element = ap.x (lo broadcast)
          pk_fma_lo(accA2[r][0], ap, make_float2(wlo0.x, wlo0.y));
          pk_fma_lo(accA2[r][1], ap, make_float2(wlo0.z, wlo0.w));
          pk_fma_lo(accB2[r][0], ap, make_float2(whi0.x, whi0.y));
          pk_fma_lo(accB2[r][1], ap, make_float2(whi0.z, whi0.w));
          // k = k_even+1: A element = ap.y (hi broadcast)
          pk_fma_hi(accA2[r][0], ap, make_float2(wlo1.x, wlo1.y));
          pk_fma_hi(accA2[r][1], ap, make_float2(wlo1.z, wlo1.w));
          pk_fma_hi(accB2[r][0], ap, make_float2(whi1.x, whi1.y));
          pk_fma_hi(accB2[r][1], ap, make_float2(whi1.z, whi1.w));
        }
      }
    }
    __syncthreads();
  }

  // --- epilogue ---
  float4 blo = make_float4(0.f, 0.f, 0.f, 0.f);
  float4 bhi;
  if (MODE == 0) {
    blo = *(const float4*)&bias[j0];
    bhi = *(const float4*)&bias[64 + j0];
  } else {
    bhi = *(const float4*)&bias[j0];  // bias applies to r (upper half)
  }
#pragma unroll
  for (int r = 0; r < 4; ++r) {
    const int grow = row0 + r0 + r;
    if (grow >= NNODES) continue;
    float4 lo = make_float4(accA2[r][0].x + blo.x, accA2[r][0].y + blo.y,
                            accA2[r][1].x + blo.z, accA2[r][1].y + blo.w);
    float4 hi = make_float4(accB2[r][0].x + bhi.x, accB2[r][0].y + bhi.y,
                            accB2[r][1].x + bhi.z, accB2[r][1].y + bhi.w);
    if (MODE == 0) {
      lo.x = fmaxf(lo.x, 0.f); lo.y = fmaxf(lo.y, 0.f);
      lo.z = fmaxf(lo.z, 0.f); lo.w = fmaxf(lo.w, 0.f);
      hi.x = fmaxf(hi.x, 0.f); hi.y = fmaxf(hi.y, 0.f);
      hi.z = fmaxf(hi.z, 0.f); hi.w = fmaxf(hi.w, 0.f);
      *(float4*)&O0[(size_t)grow * 128 + j0] = lo;
      *(float4*)&O0[(size_t)grow * 128 + 64 + j0] = hi;
    } else {
      ushort4 ob;
      ob.x = f2bf(lo.x); ob.y = f2bf(lo.y); ob.z = f2bf(lo.z); ob.w = f2bf(lo.w);
      *(ushort4*)&PB[(size_t)grow * 64 + j0] = ob;  // p as bf16 (gather operand)
      *(float4*)&O1[(size_t)grow * 64 + j0] = hi;   // r (+bl2), fp32
    }
  }
}

}  // namespace

extern "C" void kernel_launch(void* const* d_in, const int* in_sizes, int n_in,
                              void* d_out, int out_size, void* d_ws, size_t ws_size,
                              hipStream_t stream) {
  const float* x   = (const float*)d_in[0];
  const void*  ei  = d_in[1];  // edge_index, int32 or int64 (detected in-block)
  const float* Wl1 = (const float*)d_in[2];
  const float* bl1 = (const float*)d_in[3];
  const float* Wr1 = (const float*)d_in[4];
  const float* Wl2 = (const float*)d_in[5];
  const float* bl2 = (const float*)d_in[6];
  const float* Wr2 = (const float*)d_in[7];
  float* out = (float*)d_out;

  // Workspace layout (bytes):
  //   blkhist [NBUCK*SB]   int32 @ 0          (100,352 padded)
  //   offs    [NBUCK*SB]   int32 @ 100,352    (100,352 padded)
  //   bcount  [NBUCK]      int32 @ 200,704    (2,048)
  //   bprefix [NBUCK]      int32 @ 202,752    (2,048)
  //   row_ptr [N+1]        int32 @ 204,800    (200,192 padded)
  //   col     [E]          int32 @ 404,992    (3,200,000)
  //   ebuf    [NBUCK*BCAP] u32   @ 3,604,992  (4,804,608)
  //   xb      [N,64]       bf16  @ 8,409,600  (6,400,000)
  //   pb      [N,64]       bf16  @ 14,809,600 (6,400,000)
  //   mean1   [N,64]       f32   @ 21,209,600 (12,800,000)  -- reused as r
  //   h       [N,128]      f32   @ 34,009,600 (25,600,000)
  // total: 59,609,600 bytes. No memsets: every buffer fully written before read.
  char* ws = (char*)d_ws;
  int*            blkhist = (int*)(ws + 0);
  int*            offs    = (int*)(ws + 100352);
  int*            bcount  = (int*)(ws + 200704);
  int*            bprefix = (int*)(ws + 202752);
  int*            row_ptr = (int*)(ws + 204800);
  int*            col     = (int*)(ws + 404992);
  unsigned int*   ebuf    = (unsigned int*)(ws + 3604992);
  unsigned short* xb      = (unsigned short*)(ws + 8409600);
  unsigned short* pb      = (unsigned short*)(ws + 14809600);
  float*          mean1   = (float*)(ws + 21209600);
  float*          h       = (float*)(ws + 34009600);
  float*          r       = mean1;  // safe: mean1's last read (gemm128<0>) precedes gemm128<1>'s write

  // bf16 copy of x for the layer-1 gather (independent; runs while CSR builds)
  x_to_bf16<<<1024, 256, 0, stream>>>(x, xb);

  // CSR build: histogram -> per-bucket offsets -> bucketed scatter ->
  // in-bucket sort + row_ptr emit. Zero global atomics, zero memsets.
  hist_pass<<<SB, 512, 0, stream>>>(ei, blkhist);
  col_scan<<<NBUCK, 64, 0, stream>>>(blkhist, offs, bcount);
  bucket_prefix<<<1, 512, 0, stream>>>(bcount, bprefix);
  scatter_pass<<<SB, 512, 0, stream>>>(ei, offs, ebuf);
  csr_emit2<<<NBUCK, 256, 0, stream>>>(ebuf, bcount, bprefix, row_ptr, col);

  constexpr int GEMM_BLOCKS = (NNODES + 63) / 64;  // 782

  // Layer 1: mean-aggregate x (node-parallel dual-edge bf16 gather), then
  // fused linear+relu (packed-fp32 GEMM)
  seg_mean_bf<false><<<12500, 256, 0, stream>>>((const unsigned int*)xb, row_ptr, col,
                                                nullptr, mean1);
  gemm128<0><<<GEMM_BLOCKS, 256, 0, stream>>>(mean1, x, Wl1, Wr1, bl1, h, nullptr, nullptr);

  // Layer 2: project first (mean commutes with linear; p emitted as bf16),
  // then gather + fused add of r
  gemm128<1><<<GEMM_BLOCKS, 256, 0, stream>>>(h, nullptr, Wl2, Wr2, bl2, nullptr, r, pb);
  seg_mean_bf<true><<<12500, 256, 0, stream>>>((const unsigned int*)pb, row_ptr, col,
                                               r, out);
}